// Round 4
// baseline (169.656 us; speedup 1.0000x reference)
//
#include <hip/hip_runtime.h>
#include <math.h>

#define BB   512
#define TT   256
#define EMBD 364
#define HS   64
#define KPAD 384
#define NC   192

typedef __attribute__((ext_vector_type(8))) short short8_t;  // 8 bf16
typedef __attribute__((ext_vector_type(4))) float f32x4;

__device__ __forceinline__ ushort f2bf(float v) {
    union { float f; unsigned u; } c; c.f = v;
    unsigned b = c.u;
    return (ushort)((b + 0x7FFF + ((b >> 16) & 1)) >> 16);   // RNE
}

// ---------------- d_ws layout (bytes) ----------------
#define WT_BYTES  ((size_t)NC * KPAD * 2)            // 147456
#define KQ_ELEMS  ((size_t)BB * TT * HS)             // 8388608
#define K_OFF_B   (WT_BYTES)
#define Q_OFF_B   (K_OFF_B + KQ_ELEMS * 2)
#define VT_OFF_B  (Q_OFF_B + KQ_ELEMS * 2)
#define WS_NEEDED (VT_OFF_B + KQ_ELEMS * 2)          // 50,479,104 B

// ---------- kernel 0: W -> bf16 W^T [192][384], k-part pre-scaled by 0.125 ----------
__global__ void prep_wt(const float* __restrict__ Wk, const float* __restrict__ Wq,
                        const float* __restrict__ Wv, ushort* __restrict__ WT)
{
    const int c = blockIdx.x;                 // 0..191 output col of [k|q|v]
    const float* Wp = (c < 64) ? Wk : (c < 128 ? Wq : Wv);
    const float s  = (c < 64) ? 0.125f : 1.0f;
    const int col  = c & 63;
    for (int e = threadIdx.x; e < KPAD; e += 64) {
        float v = (e < EMBD) ? Wp[(size_t)e * HS + col] * s : 0.f;
        WT[(size_t)c * KPAD + e] = f2bf(v);
    }
}

// ================= Kernel A: zero-LDS streaming projection GEMM =================
// grid 2048 blocks (64 M-rows each) x 256 thr (4 waves). wave tile = 32M x 96N.
__global__ __launch_bounds__(256, 4) void proj_gemm(
    const float* __restrict__ x, const ushort* __restrict__ WT,
    const float* __restrict__ bk_, const float* __restrict__ bq_,
    const float* __restrict__ bv_,
    ushort* __restrict__ Kg, ushort* __restrict__ Qg, ushort* __restrict__ Vt)
{
    const int blk = blockIdx.x;
    const int tid = threadIdx.x;
    const int l   = tid & 63;
    const int w   = tid >> 6;
    const int l15 = l & 15;
    const int lg  = l >> 4;
    const int mh  = w >> 1;          // M half (32 rows)
    const int nh  = w & 1;           // N half (96 cols)

    const size_t row0 = (size_t)blk * 64 + mh * 32;   // + mi*16 + l15

    f32x4 acc[2][6];
    #pragma unroll
    for (int mi = 0; mi < 2; ++mi)
        #pragma unroll
        for (int j = 0; j < 6; ++j) acc[mi][j] = (f32x4){0.f, 0.f, 0.f, 0.f};

    for (int kc = 0; kc < 12; ++kc) {
        const int k0 = kc * 32;
        short8_t a[2];
        if (kc < 11) {
            #pragma unroll
            for (int mi = 0; mi < 2; ++mi) {
                const float* xr = x + (row0 + mi * 16 + l15) * EMBD + k0 + lg * 8;
                float4 f0 = *(const float4*)xr;
                float4 f1 = *(const float4*)(xr + 4);
                union { short8_t s; ushort u[8]; } pk;
                pk.u[0] = f2bf(f0.x); pk.u[1] = f2bf(f0.y);
                pk.u[2] = f2bf(f0.z); pk.u[3] = f2bf(f0.w);
                pk.u[4] = f2bf(f1.x); pk.u[5] = f2bf(f1.y);
                pk.u[6] = f2bf(f1.z); pk.u[7] = f2bf(f1.w);
                a[mi] = pk.s;
            }
        } else {
            #pragma unroll
            for (int mi = 0; mi < 2; ++mi) {
                const float* xr = x + (row0 + mi * 16 + l15) * EMBD;
                union { short8_t s; ushort u[8]; } pk;
                #pragma unroll
                for (int u2 = 0; u2 < 8; ++u2) {
                    int k = k0 + lg * 8 + u2;
                    pk.u[u2] = (k < EMBD) ? f2bf(xr[k]) : (ushort)0;
                }
                a[mi] = pk.s;
            }
        }
        #pragma unroll
        for (int j = 0; j < 6; ++j) {
            short8_t bf = *(const short8_t*)&WT[(size_t)(nh * 96 + j * 16 + l15) * KPAD + k0 + lg * 8];
            acc[0][j] = __builtin_amdgcn_mfma_f32_16x16x32_bf16(a[0], bf, acc[0][j], 0, 0, 0);
            acc[1][j] = __builtin_amdgcn_mfma_f32_16x16x32_bf16(a[1], bf, acc[1][j], 0, 0, 0);
        }
    }

    // epilogue: +bias (k pre-scaled), store bf16 K/Q normal, V transposed per batch
    const int b   = blk >> 2;
    const int tl0 = (blk & 3) * 64 + mh * 32;  // t local to batch
    #pragma unroll
    for (int j = 0; j < 6; ++j) {
        const int c = nh * 96 + j * 16 + l15;
        const float bias = (c < 64) ? bk_[c] * 0.125f
                         : (c < 128 ? bq_[c - 64] : bv_[c - 128]);
        #pragma unroll
        for (int mi = 0; mi < 2; ++mi) {
            const size_t trow = row0 + mi * 16 + lg * 4;
            if (c < 64) {
                #pragma unroll
                for (int r = 0; r < 4; ++r)
                    Kg[(trow + r) * HS + c] = f2bf(acc[mi][j][r] + bias);
            } else if (c < 128) {
                #pragma unroll
                for (int r = 0; r < 4; ++r)
                    Qg[(trow + r) * HS + (c - 64)] = f2bf(acc[mi][j][r] + bias);
            } else {
                ushort4 pk;
                pk.x = f2bf(acc[mi][j][0] + bias);
                pk.y = f2bf(acc[mi][j][1] + bias);
                pk.z = f2bf(acc[mi][j][2] + bias);
                pk.w = f2bf(acc[mi][j][3] + bias);
                const int tloc = tl0 + mi * 16 + lg * 4;
                *(ushort4*)&Vt[((size_t)b * HS + (c - 128)) * TT + tloc] = pk;
            }
        }
    }
}

// ================= Kernel B: per-batch causal flash attention, no barriers =================
__global__ __launch_bounds__(512, 4) void attn_fused(
    const ushort* __restrict__ Kg, const ushort* __restrict__ Qg,
    const ushort* __restrict__ Vt, float* __restrict__ out)
{
    const int b   = blockIdx.x;
    const int tid = threadIdx.x;
    const int l   = tid & 63;
    const int w   = tid >> 6;
    const int l15 = l & 15;
    const int lg  = l >> 4;

    __shared__ ushort pb[8][16 * 40];
    ushort* pbw = pb[w];

    const ushort* Kb = Kg + (size_t)b * TT * HS;
    const ushort* Qb = Qg + (size_t)b * TT * HS;
    const ushort* Vb = Vt + (size_t)b * HS * TT;

    #pragma unroll
    for (int half = 0; half < 2; ++half) {
        const int rt = half ? (15 - w) : w;     // balanced causal work: 9 chunks/wave
        const int t0 = rt * 16;

        short8_t afr[2];                        // K A-frags, constant over chunks
        afr[0] = *(const short8_t*)&Kb[(t0 + l15) * HS + lg * 8];
        afr[1] = *(const short8_t*)&Kb[(t0 + l15) * HS + 32 + lg * 8];

        float mr[4], lr[4];
        f32x4 o[4];
        #pragma unroll
        for (int r = 0; r < 4; ++r) { mr[r] = -INFINITY; lr[r] = 0.f; }
        #pragma unroll
        for (int nt = 0; nt < 4; ++nt) o[nt] = (f32x4){0.f, 0.f, 0.f, 0.f};

        const int jd = t0 >> 5;
        for (int j = 0; j <= jd; ++j) {
            const int sb = j * 32;
            f32x4 sacc[2];
            sacc[0] = (f32x4){0.f, 0.f, 0.f, 0.f};
            sacc[1] = (f32x4){0.f, 0.f, 0.f, 0.f};
            #pragma unroll
            for (int kk = 0; kk < 2; ++kk) {
                #pragma unroll
                for (int ct = 0; ct < 2; ++ct) {
                    short8_t bfr = *(const short8_t*)&Qb[(sb + ct * 16 + l15) * HS + kk * 32 + lg * 8];
                    sacc[ct] = __builtin_amdgcn_mfma_f32_16x16x32_bf16(afr[kk], bfr, sacc[ct], 0, 0, 0);
                }
            }
            #pragma unroll
            for (int ct = 0; ct < 2; ++ct) {
                int s = sb + ct * 16 + l15;
                #pragma unroll
                for (int r = 0; r < 4; ++r) {
                    int t = t0 + lg * 4 + r;
                    if (s > t) sacc[ct][r] = -INFINITY;
                }
            }
            float p0[4], p1[4], fsc[4];
            #pragma unroll
            for (int r = 0; r < 4; ++r) {
                float mx = fmaxf(sacc[0][r], sacc[1][r]);
                mx = fmaxf(mx, __shfl_xor(mx, 1));
                mx = fmaxf(mx, __shfl_xor(mx, 2));
                mx = fmaxf(mx, __shfl_xor(mx, 4));
                mx = fmaxf(mx, __shfl_xor(mx, 8));
                float nm = fmaxf(mr[r], mx);
                fsc[r] = __expf(mr[r] - nm);
                mr[r] = nm;
                p0[r] = __expf(sacc[0][r] - nm);
                p1[r] = __expf(sacc[1][r] - nm);
                float ps = p0[r] + p1[r];
                ps += __shfl_xor(ps, 1);
                ps += __shfl_xor(ps, 2);
                ps += __shfl_xor(ps, 4);
                ps += __shfl_xor(ps, 8);
                lr[r] = lr[r] * fsc[r] + ps;
            }
            #pragma unroll
            for (int nt = 0; nt < 4; ++nt)
                #pragma unroll
                for (int r = 0; r < 4; ++r) o[nt][r] *= fsc[r];
            #pragma unroll
            for (int r = 0; r < 4; ++r) {
                pbw[(lg * 4 + r) * 40 + l15]      = f2bf(p0[r]);
                pbw[(lg * 4 + r) * 40 + 16 + l15] = f2bf(p1[r]);
            }
            short8_t pa = *(const short8_t*)&pbw[l15 * 40 + lg * 8];
            #pragma unroll
            for (int nt = 0; nt < 4; ++nt) {
                short8_t bfr = *(const short8_t*)&Vb[(nt * 16 + l15) * TT + sb + lg * 8];
                o[nt] = __builtin_amdgcn_mfma_f32_16x16x32_bf16(pa, bfr, o[nt], 0, 0, 0);
            }
        }
        #pragma unroll
        for (int r = 0; r < 4; ++r) {
            float inv = 1.0f / lr[r];
            int t = t0 + lg * 4 + r;
            float* op = out + ((size_t)b * TT + t) * HS;
            #pragma unroll
            for (int nt = 0; nt < 4; ++nt)
                op[nt * 16 + l15] = o[nt][r] * inv;
        }
    }
}

// =====================================================================================
// ===================== FALLBACK: R3 fused kernel (if ws too small) ===================
// =====================================================================================
#define LDX 136
#define XSH_OFF 0
#define WSH_OFF (TT * LDX)
#define KB_OFF  0
#define QB_OFF  (TT * 72)
#define VBT_OFF (QB_OFF + TT * 72)
#define PB_OFF  (VBT_OFF + 64 * 264)
#define LDS_USHORT (WSH_OFF + NC * LDX)
#define LDS_BYTES  (LDS_USHORT * 2)

__global__ __launch_bounds__(512, 2) void head_mfma(
    const float* __restrict__ x, const ushort* __restrict__ WT,
    const float* __restrict__ bk_, const float* __restrict__ bq_,
    const float* __restrict__ bv_, float* __restrict__ out)
{
    const int b   = blockIdx.x;
    const int tid = threadIdx.x;
    const int l   = tid & 63;
    const int w   = tid >> 6;
    const int l15 = l & 15;
    const int lg  = l >> 4;

    extern __shared__ ushort sm[];
    ushort* xsh = sm + XSH_OFF;
    ushort* wsh = sm + WSH_OFF;
    ushort* kb  = sm + KB_OFF;
    ushort* qb  = sm + QB_OFF;
    ushort* vbT = sm + VBT_OFF;
    ushort* pbw = sm + PB_OFF + w * (16 * 40);

    const float* xb = x + (size_t)b * TT * EMBD;
    const int nhalf = w & 1;
    const int msub  = w >> 1;

    float bias6[6];
    #pragma unroll
    for (int j = 0; j < 6; ++j) {
        int c = (nhalf * 6 + j) * 16 + l15;
        bias6[j] = (c < 64) ? bk_[c] * 0.125f : (c < 128 ? bq_[c - 64] : bv_[c - 128]);
    }

    f32x4 acc[4][6];
    #pragma unroll
    for (int mi = 0; mi < 4; ++mi)
        #pragma unroll
        for (int j = 0; j < 6; ++j) acc[mi][j] = (f32x4){0.f, 0.f, 0.f, 0.f};

    for (int kc = 0; kc < 3; ++kc) {
        const int K0 = kc * 128;
        __syncthreads();
        #pragma unroll
        for (int it = 0; it < 8; ++it) {
            int r  = it * 32 + (tid >> 4);
            int c8 = (tid & 15) * 8;
            float v[8];
            if (kc < 2) {
                float4 a0 = *(const float4*)&xb[(size_t)r * EMBD + K0 + c8];
                float4 a1 = *(const float4*)&xb[(size_t)r * EMBD + K0 + c8 + 4];
                v[0] = a0.x; v[1] = a0.y; v[2] = a0.z; v[3] = a0.w;
                v[4] = a1.x; v[5] = a1.y; v[6] = a1.z; v[7] = a1.w;
            } else {
                #pragma unroll
                for (int u = 0; u < 8; ++u) {
                    int e = K0 + c8 + u;
                    v[u] = (e < EMBD) ? xb[(size_t)r * EMBD + e] : 0.f;
                }
            }
            union { short8_t s8; ushort us[8]; } pk;
            #pragma unroll
            for (int u = 0; u < 8; ++u) pk.us[u] = f2bf(v[u]);
            *(short8_t*)&xsh[r * LDX + c8] = pk.s8;
        }
        if (tid < 384) {
            int rc = tid >> 1, ch = tid & 1;
            #pragma unroll
            for (int u = 0; u < 8; ++u) {
                short8_t wv = *(const short8_t*)&WT[(size_t)rc * KPAD + K0 + ch * 64 + u * 8];
                *(short8_t*)&wsh[rc * LDX + ch * 64 + u * 8] = wv;
            }
        }
        __syncthreads();
        #pragma unroll
        for (int ks = 0; ks < 4; ++ks) {
            short8_t a[4];
            #pragma unroll
            for (int mi = 0; mi < 4; ++mi)
                a[mi] = *(const short8_t*)&xsh[(mi * 64 + msub * 16 + l15) * LDX + ks * 32 + lg * 8];
            #pragma unroll
            for (int j = 0; j < 6; ++j) {
                short8_t bf = *(const short8_t*)&wsh[((nhalf * 6 + j) * 16 + l15) * LDX + ks * 32 + lg * 8];
                #pragma unroll
                for (int mi = 0; mi < 4; ++mi)
                    acc[mi][j] = __builtin_amdgcn_mfma_f32_16x16x32_bf16(a[mi], bf, acc[mi][j], 0, 0, 0);
            }
        }
    }
    __syncthreads();

    #pragma unroll
    for (int mi = 0; mi < 4; ++mi)
        #pragma unroll
        for (int j = 0; j < 6; ++j) {
            int c = (nhalf * 6 + j) * 16 + l15;
            #pragma unroll
            for (int r = 0; r < 4; ++r) {
                int t = mi * 64 + msub * 16 + lg * 4 + r;
                float val = acc[mi][j][r] + bias6[j];
                if (c < 64)       kb[t * 72 + c]           = f2bf(val);
                else if (c < 128) qb[t * 72 + (c - 64)]    = f2bf(val);
                else              vbT[(c - 128) * 264 + t] = f2bf(val);
            }
        }
    __syncthreads();

    #pragma unroll
    for (int half = 0; half < 2; ++half) {
        const int rt = half ? (15 - w) : w;
        const int t0 = rt * 16;
        float mr[4], lr[4];
        f32x4 o[4];
        #pragma unroll
        for (int r = 0; r < 4; ++r) { mr[r] = -INFINITY; lr[r] = 0.f; }
        #pragma unroll
        for (int nt = 0; nt < 4; ++nt) o[nt] = (f32x4){0.f, 0.f, 0.f, 0.f};

        const int jd = t0 >> 5;
        for (int j = 0; j <= jd; ++j) {
            const int sb = j * 32;
            f32x4 sacc[2];
            sacc[0] = (f32x4){0.f, 0.f, 0.f, 0.f};
            sacc[1] = (f32x4){0.f, 0.f, 0.f, 0.f};
            #pragma unroll
            for (int kk = 0; kk < 2; ++kk) {
                short8_t afr = *(const short8_t*)&kb[(t0 + l15) * 72 + kk * 32 + lg * 8];
                #pragma unroll
                for (int ct = 0; ct < 2; ++ct) {
                    short8_t bfr = *(const short8_t*)&qb[(sb + ct * 16 + l15) * 72 + kk * 32 + lg * 8];
                    sacc[ct] = __builtin_amdgcn_mfma_f32_16x16x32_bf16(afr, bfr, sacc[ct], 0, 0, 0);
                }
            }
            #pragma unroll
            for (int ct = 0; ct < 2; ++ct) {
                int s = sb + ct * 16 + l15;
                #pragma unroll
                for (int r = 0; r < 4; ++r) {
                    int t = t0 + lg * 4 + r;
                    if (s > t) sacc[ct][r] = -INFINITY;
                }
            }
            float p0[4], p1[4], fsc[4];
            #pragma unroll
            for (int r = 0; r < 4; ++r) {
                float mx = fmaxf(sacc[0][r], sacc[1][r]);
                mx = fmaxf(mx, __shfl_xor(mx, 1));
                mx = fmaxf(mx, __shfl_xor(mx, 2));
                mx = fmaxf(mx, __shfl_xor(mx, 4));
                mx = fmaxf(mx, __shfl_xor(mx, 8));
                float nm = fmaxf(mr[r], mx);
                fsc[r] = __expf(mr[r] - nm);
                mr[r] = nm;
                p0[r] = __expf(sacc[0][r] - nm);
                p1[r] = __expf(sacc[1][r] - nm);
                float ps = p0[r] + p1[r];
                ps += __shfl_xor(ps, 1);
                ps += __shfl_xor(ps, 2);
                ps += __shfl_xor(ps, 4);
                ps += __shfl_xor(ps, 8);
                lr[r] = lr[r] * fsc[r] + ps;
            }
            #pragma unroll
            for (int nt = 0; nt < 4; ++nt)
                #pragma unroll
                for (int r = 0; r < 4; ++r) o[nt][r] *= fsc[r];
            #pragma unroll
            for (int r = 0; r < 4; ++r) {
                pbw[(lg * 4 + r) * 40 + l15]      = f2bf(p0[r]);
                pbw[(lg * 4 + r) * 40 + 16 + l15] = f2bf(p1[r]);
            }
            short8_t pa = *(const short8_t*)&pbw[l15 * 40 + lg * 8];
            #pragma unroll
            for (int nt = 0; nt < 4; ++nt) {
                short8_t bfr = *(const short8_t*)&vbT[(nt * 16 + l15) * 264 + sb + lg * 8];
                o[nt] = __builtin_amdgcn_mfma_f32_16x16x32_bf16(pa, bfr, o[nt], 0, 0, 0);
            }
        }
        #pragma unroll
        for (int r = 0; r < 4; ++r) {
            float inv = 1.0f / lr[r];
            int t = t0 + lg * 4 + r;
            float* op = out + ((size_t)b * TT + t) * HS;
            #pragma unroll
            for (int nt = 0; nt < 4; ++nt)
                op[nt * 16 + l15] = o[nt][r] * inv;
        }
    }
}

extern "C" void kernel_launch(void* const* d_in, const int* in_sizes, int n_in,
                              void* d_out, int out_size, void* d_ws, size_t ws_size,
                              hipStream_t stream) {
    const float* x  = (const float*)d_in[0];
    const float* Wk = (const float*)d_in[1];
    const float* bk = (const float*)d_in[2];
    const float* Wq = (const float*)d_in[3];
    const float* bq = (const float*)d_in[4];
    const float* Wv = (const float*)d_in[5];
    const float* bv = (const float*)d_in[6];
    float* out = (float*)d_out;

    ushort* WT = (ushort*)d_ws;
    prep_wt<<<dim3(NC), dim3(64), 0, stream>>>(Wk, Wq, Wv, WT);

    if (ws_size >= WS_NEEDED) {
        ushort* Kg = (ushort*)((char*)d_ws + K_OFF_B);
        ushort* Qg = (ushort*)((char*)d_ws + Q_OFF_B);
        ushort* Vt = (ushort*)((char*)d_ws + VT_OFF_B);
        proj_gemm<<<dim3(2048), dim3(256), 0, stream>>>(x, WT, bk, bq, bv, Kg, Qg, Vt);
        attn_fused<<<dim3(BB), dim3(512), 0, stream>>>(Kg, Qg, Vt, out);
    } else {
        hipFuncSetAttribute((const void*)head_mfma,
                            hipFuncAttributeMaxDynamicSharedMemorySize, LDS_BYTES);
        head_mfma<<<dim3(BB), dim3(512), LDS_BYTES, stream>>>(x, WT, bk, bq, bv, out);
    }
}

// Round 5
// 128.042 us; speedup vs baseline: 1.3250x; 1.3250x over previous
//
#include <hip/hip_runtime.h>
#include <math.h>

#define BB   512
#define TT   256
#define EMBD 364
#define HS   64
#define KPAD 384
#define NC   192
#define LP   72      // LDS x-tile pitch (ushorts); 144 B -> uniform bank spread

typedef __attribute__((ext_vector_type(8))) short short8_t;  // 8 bf16
typedef __attribute__((ext_vector_type(4))) float f32x4;

__device__ __forceinline__ ushort f2bf(float v) {
    union { float f; unsigned u; } c; c.f = v;
    unsigned b = c.u;
    return (ushort)((b + 0x7FFF + ((b >> 16) & 1)) >> 16);   // RNE
}

// ---------------- d_ws layout (bytes) ----------------
#define WT_BYTES  ((size_t)NC * KPAD * 2)            // 147456
#define KQ_ELEMS  ((size_t)BB * TT * HS)             // 8388608
#define K_OFF_B   (WT_BYTES)
#define Q_OFF_B   (K_OFF_B + KQ_ELEMS * 2)
#define VT_OFF_B  (Q_OFF_B + KQ_ELEMS * 2)
#define WS_NEEDED (VT_OFF_B + KQ_ELEMS * 2)          // ~50.5 MB (fits: R4 ran this path)

// ---------- kernel 0: W -> bf16 W^T [192][384], k-part pre-scaled by 0.125 ----------
__global__ void prep_wt(const float* __restrict__ Wk, const float* __restrict__ Wq,
                        const float* __restrict__ Wv, ushort* __restrict__ WT)
{
    const int c = blockIdx.x;
    const float* Wp = (c < 64) ? Wk : (c < 128 ? Wq : Wv);
    const float s  = (c < 64) ? 0.125f : 1.0f;
    const int col  = c & 63;
    for (int e = threadIdx.x; e < KPAD; e += 64) {
        float v = (e < EMBD) ? Wp[(size_t)e * HS + col] * s : 0.f;
        WT[(size_t)c * KPAD + e] = f2bf(v);
    }
}

// ================= Kernel A: LDS-staged streaming projection GEMM =================
// 2048 blocks x 256 thr (4 waves). Block: 64 M-rows, full N=192, K in 6 chunks of 64.
// Wave tile = 64M x 48N. x staged coalesced -> bf16 LDS (double buffer); W from L2.
__global__ __launch_bounds__(256, 4) void proj_gemm(
    const float* __restrict__ x, const ushort* __restrict__ WT,
    const float* __restrict__ bk_, const float* __restrict__ bq_,
    const float* __restrict__ bv_,
    ushort* __restrict__ Kg, ushort* __restrict__ Qg, ushort* __restrict__ Vt)
{
    const int blk = blockIdx.x;
    const int tid = threadIdx.x;
    const int l   = tid & 63;
    const int w   = tid >> 6;
    const int l15 = l & 15;
    const int lg  = l >> 4;

    __shared__ ushort xs[2][64 * LP];

    const float* xb = x + (size_t)blk * 64 * EMBD;
    const int srow = tid >> 2;          // 0..63
    const int scol = (tid & 3) * 16;    // 0/16/32/48

    float sreg[16];

    // --- staging helpers ---
    auto LOAD = [&](int kc) {
        const int k0 = kc * 64;
        if (kc < 5) {
            #pragma unroll
            for (int u = 0; u < 4; ++u) {
                float4 f = *(const float4*)&xb[(size_t)srow * EMBD + k0 + scol + u * 4];
                sreg[u * 4 + 0] = f.x; sreg[u * 4 + 1] = f.y;
                sreg[u * 4 + 2] = f.z; sreg[u * 4 + 3] = f.w;
            }
        } else {
            #pragma unroll
            for (int u = 0; u < 16; ++u) {
                int k = k0 + scol + u;
                sreg[u] = (k < EMBD) ? xb[(size_t)srow * EMBD + k] : 0.f;
            }
        }
    };
    auto WRITE = [&](int buf) {
        union { short8_t s8; ushort u[8]; } p0, p1;
        #pragma unroll
        for (int u = 0; u < 8; ++u) { p0.u[u] = f2bf(sreg[u]); p1.u[u] = f2bf(sreg[8 + u]); }
        *(short8_t*)&xs[buf][srow * LP + scol]     = p0.s8;
        *(short8_t*)&xs[buf][srow * LP + scol + 8] = p1.s8;
    };

    f32x4 acc[4][3];
    #pragma unroll
    for (int mi = 0; mi < 4; ++mi)
        #pragma unroll
        for (int j = 0; j < 3; ++j) acc[mi][j] = (f32x4){0.f, 0.f, 0.f, 0.f};

    LOAD(0); WRITE(0);
    __syncthreads();

    for (int kc = 0; kc < 6; ++kc) {
        if (kc < 5) LOAD(kc + 1);              // issue next chunk's global loads early
        const int buf = kc & 1;
        #pragma unroll
        for (int ks = 0; ks < 2; ++ks) {
            short8_t a[4];
            #pragma unroll
            for (int mi = 0; mi < 4; ++mi)
                a[mi] = *(const short8_t*)&xs[buf][(mi * 16 + l15) * LP + ks * 32 + lg * 8];
            #pragma unroll
            for (int j = 0; j < 3; ++j) {
                const int c = w * 48 + j * 16 + l15;
                short8_t bf = *(const short8_t*)&WT[(size_t)c * KPAD + kc * 64 + ks * 32 + lg * 8];
                #pragma unroll
                for (int mi = 0; mi < 4; ++mi)
                    acc[mi][j] = __builtin_amdgcn_mfma_f32_16x16x32_bf16(a[mi], bf, acc[mi][j], 0, 0, 0);
            }
        }
        if (kc < 5) WRITE(1 - buf);            // other buffer: safe (readers done at prev barrier)
        __syncthreads();
    }

    // --- epilogue: +bias (k pre-scaled), K/Q row-major, V transposed per batch ---
    const int b   = blk >> 2;
    const int tl0 = (blk & 3) * 64;
    #pragma unroll
    for (int j = 0; j < 3; ++j) {
        const int c = w * 48 + j * 16 + l15;
        const float bias = (c < 64) ? bk_[c] * 0.125f
                         : (c < 128 ? bq_[c - 64] : bv_[c - 128]);
        #pragma unroll
        for (int mi = 0; mi < 4; ++mi) {
            const size_t trow = (size_t)blk * 64 + mi * 16 + lg * 4;
            if (c < 64) {
                #pragma unroll
                for (int r = 0; r < 4; ++r)
                    Kg[(trow + r) * HS + c] = f2bf(acc[mi][j][r] + bias);
            } else if (c < 128) {
                #pragma unroll
                for (int r = 0; r < 4; ++r)
                    Qg[(trow + r) * HS + (c - 64)] = f2bf(acc[mi][j][r] + bias);
            } else {
                ushort4 pk;
                pk.x = f2bf(acc[mi][j][0] + bias);
                pk.y = f2bf(acc[mi][j][1] + bias);
                pk.z = f2bf(acc[mi][j][2] + bias);
                pk.w = f2bf(acc[mi][j][3] + bias);
                const int tloc = tl0 + mi * 16 + lg * 4;
                *(ushort4*)&Vt[((size_t)b * HS + (c - 128)) * TT + tloc] = pk;
            }
        }
    }
}

// ================= Kernel B: per-batch causal flash attention, no barriers =================
__global__ __launch_bounds__(512, 4) void attn_fused(
    const ushort* __restrict__ Kg, const ushort* __restrict__ Qg,
    const ushort* __restrict__ Vt, float* __restrict__ out)
{
    const int b   = blockIdx.x;
    const int tid = threadIdx.x;
    const int l   = tid & 63;
    const int w   = tid >> 6;
    const int l15 = l & 15;
    const int lg  = l >> 4;

    __shared__ ushort pb[8][16 * 40];
    ushort* pbw = pb[w];

    const ushort* Kb = Kg + (size_t)b * TT * HS;
    const ushort* Qb = Qg + (size_t)b * TT * HS;
    const ushort* Vb = Vt + (size_t)b * HS * TT;

    #pragma unroll
    for (int half = 0; half < 2; ++half) {
        const int rt = half ? (15 - w) : w;     // balanced causal work: 9 chunks/wave
        const int t0 = rt * 16;

        short8_t afr[2];
        afr[0] = *(const short8_t*)&Kb[(t0 + l15) * HS + lg * 8];
        afr[1] = *(const short8_t*)&Kb[(t0 + l15) * HS + 32 + lg * 8];

        float mr[4], lr[4];
        f32x4 o[4];
        #pragma unroll
        for (int r = 0; r < 4; ++r) { mr[r] = -INFINITY; lr[r] = 0.f; }
        #pragma unroll
        for (int nt = 0; nt < 4; ++nt) o[nt] = (f32x4){0.f, 0.f, 0.f, 0.f};

        const int jd = t0 >> 5;
        for (int j = 0; j <= jd; ++j) {
            const int sb = j * 32;
            f32x4 sacc[2];
            sacc[0] = (f32x4){0.f, 0.f, 0.f, 0.f};
            sacc[1] = (f32x4){0.f, 0.f, 0.f, 0.f};
            #pragma unroll
            for (int kk = 0; kk < 2; ++kk) {
                #pragma unroll
                for (int ct = 0; ct < 2; ++ct) {
                    short8_t bfr = *(const short8_t*)&Qb[(sb + ct * 16 + l15) * HS + kk * 32 + lg * 8];
                    sacc[ct] = __builtin_amdgcn_mfma_f32_16x16x32_bf16(afr[kk], bfr, sacc[ct], 0, 0, 0);
                }
            }
            #pragma unroll
            for (int ct = 0; ct < 2; ++ct) {
                int s = sb + ct * 16 + l15;
                #pragma unroll
                for (int r = 0; r < 4; ++r) {
                    int t = t0 + lg * 4 + r;
                    if (s > t) sacc[ct][r] = -INFINITY;
                }
            }
            float p0[4], p1[4], fsc[4];
            #pragma unroll
            for (int r = 0; r < 4; ++r) {
                float mx = fmaxf(sacc[0][r], sacc[1][r]);
                mx = fmaxf(mx, __shfl_xor(mx, 1));
                mx = fmaxf(mx, __shfl_xor(mx, 2));
                mx = fmaxf(mx, __shfl_xor(mx, 4));
                mx = fmaxf(mx, __shfl_xor(mx, 8));
                float nm = fmaxf(mr[r], mx);
                fsc[r] = __expf(mr[r] - nm);
                mr[r] = nm;
                p0[r] = __expf(sacc[0][r] - nm);
                p1[r] = __expf(sacc[1][r] - nm);
                float ps = p0[r] + p1[r];
                ps += __shfl_xor(ps, 1);
                ps += __shfl_xor(ps, 2);
                ps += __shfl_xor(ps, 4);
                ps += __shfl_xor(ps, 8);
                lr[r] = lr[r] * fsc[r] + ps;
            }
            #pragma unroll
            for (int nt = 0; nt < 4; ++nt)
                #pragma unroll
                for (int r = 0; r < 4; ++r) o[nt][r] *= fsc[r];
            #pragma unroll
            for (int r = 0; r < 4; ++r) {
                pbw[(lg * 4 + r) * 40 + l15]      = f2bf(p0[r]);
                pbw[(lg * 4 + r) * 40 + 16 + l15] = f2bf(p1[r]);
            }
            short8_t pa = *(const short8_t*)&pbw[l15 * 40 + lg * 8];
            #pragma unroll
            for (int nt = 0; nt < 4; ++nt) {
                short8_t bfr = *(const short8_t*)&Vb[(nt * 16 + l15) * TT + sb + lg * 8];
                o[nt] = __builtin_amdgcn_mfma_f32_16x16x32_bf16(pa, bfr, o[nt], 0, 0, 0);
            }
        }
        #pragma unroll
        for (int r = 0; r < 4; ++r) {
            float inv = 1.0f / lr[r];
            int t = t0 + lg * 4 + r;
            float* op = out + ((size_t)b * TT + t) * HS;
            #pragma unroll
            for (int nt = 0; nt < 4; ++nt)
                op[nt * 16 + l15] = o[nt][r] * inv;
        }
    }
}

extern "C" void kernel_launch(void* const* d_in, const int* in_sizes, int n_in,
                              void* d_out, int out_size, void* d_ws, size_t ws_size,
                              hipStream_t stream) {
    const float* x  = (const float*)d_in[0];
    const float* Wk = (const float*)d_in[1];
    const float* bk = (const float*)d_in[2];
    const float* Wq = (const float*)d_in[3];
    const float* bq = (const float*)d_in[4];
    const float* Wv = (const float*)d_in[5];
    const float* bv = (const float*)d_in[6];
    float* out = (float*)d_out;

    ushort* WT = (ushort*)d_ws;
    ushort* Kg = (ushort*)((char*)d_ws + K_OFF_B);
    ushort* Qg = (ushort*)((char*)d_ws + Q_OFF_B);
    ushort* Vt = (ushort*)((char*)d_ws + VT_OFF_B);

    prep_wt<<<dim3(NC), dim3(64), 0, stream>>>(Wk, Wq, Wv, WT);
    proj_gemm<<<dim3(2048), dim3(256), 0, stream>>>(x, WT, bk, bq, bv, Kg, Qg, Vt);
    attn_fused<<<dim3(BB), dim3(512), 0, stream>>>(Kg, Qg, Vt, out);
}